// Round 1
// baseline (384.815 us; speedup 1.0000x reference)
//
#include <hip/hip_runtime.h>

namespace {

constexpr int NB   = 32;
constexpr int NT   = 4096;
constexpr int NMEL = 128;
constexpr int ND   = 64;
constexpr int NK   = 128;
constexpr int NTOK = NB * NT;   // 131072
constexpr int BLK  = 256;       // threads per block, 1 token per thread

__global__ __launch_bounds__(BLK) void rvq_fused(
    const float* __restrict__ mel,
    const float* __restrict__ w_in,
    const float* __restrict__ b_in,
    const float* __restrict__ cb0,
    const float* __restrict__ cb1,
    const float* __restrict__ w_out,
    const float* __restrict__ b_out,
    float* __restrict__ out)
{
  // Per-block precompute of 0.5*||c_j||^2 for both codebooks (256 rows total,
  // one per thread). 1 KiB LDS; read later at wave-uniform address (broadcast).
  __shared__ float c2h[2 * NK];
  const int tid = threadIdx.x;
  {
    const float* cb = (tid < NK) ? cb0 : cb1;
    const float* cr = cb + (size_t)(tid & (NK - 1)) * ND;
    float s = 0.f;
#pragma unroll
    for (int d = 0; d < ND; ++d) { const float v = cr[d]; s += v * v; }
    c2h[tid] = 0.5f * s;
  }
  __syncthreads();

  const int t = blockIdx.x * BLK + tid;   // token id; NTOK % BLK == 0

  // ---- proj_in: z = mel_row @ w_in^T + b_in  (z[64] in VGPRs) ----
  float z[ND];
#pragma unroll
  for (int d = 0; d < ND; ++d) z[d] = b_in[d];

  const float4* __restrict__ xrow =
      reinterpret_cast<const float4*>(mel + (size_t)t * NMEL);
  for (int mc = 0; mc < NMEL / 4; ++mc) {
    const float4 xv = xrow[mc];
#pragma unroll
    for (int d = 0; d < ND; ++d) {
      // uniform address (loop counters only) -> scalar load candidate
      const float4 wv = *reinterpret_cast<const float4*>(w_in + d * NMEL + mc * 4);
      z[d] += xv.x * wv.x + xv.y * wv.y + xv.z * wv.z + xv.w * wv.w;
    }
  }

  // ---- 2-stage greedy residual VQ ----
  float r[ND];
#pragma unroll
  for (int d = 0; d < ND; ++d) r[d] = z[d];

#pragma unroll
  for (int stage = 0; stage < 2; ++stage) {
    const float* __restrict__ cb = (stage == 0) ? cb0 : cb1;
    float best = 3.0e38f;
    int bidx = 0;
    for (int j = 0; j < NK; ++j) {
      const float* __restrict__ cr = cb + j * ND;  // uniform address
      float dot = 0.f;
#pragma unroll
      for (int d = 0; d < ND; ++d) dot += r[d] * cr[d];
      // argmin(dist) == argmin(0.5*||c||^2 - r.c); strict < keeps first min,
      // matching jnp.argmin tie behavior.
      const float score = c2h[stage * NK + j] - dot;
      if (score < best) { best = score; bidx = j; }
    }
    // gather selected code (divergent index -> vector loads; cb is L1-hot)
    const float4* __restrict__ sel =
        reinterpret_cast<const float4*>(cb + (size_t)bidx * ND);
#pragma unroll
    for (int q = 0; q < ND / 4; ++q) {
      const float4 c = sel[q];
      r[4 * q + 0] -= c.x;
      r[4 * q + 1] -= c.y;
      r[4 * q + 2] -= c.z;
      r[4 * q + 3] -= c.w;
    }
  }

  // quant = z - residual ; reuse z registers
#pragma unroll
  for (int d = 0; d < ND; ++d) z[d] -= r[d];

  // ---- proj_out: out_row = quant @ w_out^T + b_out ----
  float4* __restrict__ orow = reinterpret_cast<float4*>(out + (size_t)t * NMEL);
  for (int mc = 0; mc < NMEL / 4; ++mc) {
    float a0 = b_out[mc * 4 + 0];
    float a1 = b_out[mc * 4 + 1];
    float a2 = b_out[mc * 4 + 2];
    float a3 = b_out[mc * 4 + 3];
#pragma unroll
    for (int d = 0; d < ND; ++d) {
      const float q = z[d];
      a0 += q * w_out[(mc * 4 + 0) * ND + d];
      a1 += q * w_out[(mc * 4 + 1) * ND + d];
      a2 += q * w_out[(mc * 4 + 2) * ND + d];
      a3 += q * w_out[(mc * 4 + 3) * ND + d];
    }
    float4 o;
    o.x = a0; o.y = a1; o.z = a2; o.w = a3;
    orow[mc] = o;
  }
}

}  // namespace

extern "C" void kernel_launch(void* const* d_in, const int* in_sizes, int n_in,
                              void* d_out, int out_size, void* d_ws, size_t ws_size,
                              hipStream_t stream) {
  const float* mel   = (const float*)d_in[0];
  const float* w_in  = (const float*)d_in[1];
  const float* b_in  = (const float*)d_in[2];
  const float* cb0   = (const float*)d_in[3];
  const float* cb1   = (const float*)d_in[4];
  const float* w_out = (const float*)d_in[5];
  const float* b_out = (const float*)d_in[6];
  float* out = (float*)d_out;

  dim3 grid(NTOK / BLK), block(BLK);
  hipLaunchKernelGGL(rvq_fused, grid, block, 0, stream,
                     mel, w_in, b_in, cb0, cb1, w_out, b_out, out);
}

// Round 2
// 369.241 us; speedup vs baseline: 1.0422x; 1.0422x over previous
//
#include <hip/hip_runtime.h>

namespace {

constexpr int NMEL = 128;
constexpr int ND   = 64;
constexpr int NK   = 128;
constexpr int NTOK = 32 * 4096;        // 131072 tokens
constexpr int BLK  = 256;              // threads per block
constexpr int TPB_TOK = 256;           // tokens per block (64 quads * 4)
constexpr int GRID = NTOK / TPB_TOK;   // 512 blocks

// ---------------- precompute: Dec tables + half-norms (into d_ws) ----------
// Dec0[i][m] = sum_d cb0[i][d]*w_out[m][d] + b_out[m]   (b_out folded in)
// Dec1[i][m] = sum_d cb1[i][d]*w_out[m][d]
// n0h[i] = 0.5*||cb0_i||^2 ; n1h likewise.
__global__ void precomp(const float* __restrict__ cb0,
                        const float* __restrict__ cb1,
                        const float* __restrict__ w_out,
                        const float* __restrict__ b_out,
                        float* __restrict__ dec0, float* __restrict__ dec1,
                        float* __restrict__ n0h, float* __restrict__ n1h) {
  const int i = blockIdx.x;      // code row 0..127
  const int m = threadIdx.x;     // mel column 0..127
  const float4* c0 = (const float4*)(cb0 + i * ND);
  const float4* c1 = (const float4*)(cb1 + i * ND);
  const float4* wr = (const float4*)(w_out + m * ND);
  float a0 = 0.f, a1 = 0.f;
#pragma unroll
  for (int q = 0; q < ND / 4; ++q) {
    const float4 w4 = wr[q];
    const float4 x0 = c0[q];
    const float4 x1 = c1[q];
    a0 += x0.x * w4.x + x0.y * w4.y + x0.z * w4.z + x0.w * w4.w;
    a1 += x1.x * w4.x + x1.y * w4.y + x1.z * w4.z + x1.w * w4.w;
  }
  dec0[i * NMEL + m] = a0 + b_out[m];
  dec1[i * NMEL + m] = a1;
  if (m < 2) {
    const float4* c = (m == 0) ? c0 : c1;
    float s = 0.f;
#pragma unroll
    for (int q = 0; q < ND / 4; ++q) {
      const float4 v = c[q];
      s += v.x * v.x + v.y * v.y + v.z * v.z + v.w * v.w;
    }
    ((m == 0) ? n0h : n1h)[i] = 0.5f * s;
  }
}

// ---------------- main fused kernel ----------------------------------------
// Thread decomposition: slice s = tid&3 owns dims [16s,16s+16); quad tq=tid>>2
// owns tokens [t0, t0+4). z/r for 4 tokens x 16 dims live in VGPRs. Dots are
// slice-partial, butterfly-reduced over the 4 slice lanes via __shfl_xor.
__global__ __launch_bounds__(BLK) void rvq_main(
    const float* __restrict__ mel, const float* __restrict__ w_in,
    const float* __restrict__ b_in, const float* __restrict__ cb0,
    const float* __restrict__ cb1, const float* __restrict__ dec0,
    const float* __restrict__ dec1, const float* __restrict__ n0h,
    const float* __restrict__ n1h, float* __restrict__ out) {
  const int tid = threadIdx.x;
  const int s  = tid & 3;        // dim slice 0..3
  const int tq = tid >> 2;       // token quad 0..63
  const int t0 = blockIdx.x * TPB_TOK + tq * 4;

  float z[4][16];                // 4 tokens x 16-dim slice (64 VGPRs)

  // init with bias slice
#pragma unroll
  for (int u = 0; u < 4; ++u) {
    const float4 b4 = *(const float4*)(b_in + s * 16 + u * 4);
#pragma unroll
    for (int k = 0; k < 4; ++k) {
      z[k][u * 4 + 0] = b4.x; z[k][u * 4 + 1] = b4.y;
      z[k][u * 4 + 2] = b4.z; z[k][u * 4 + 3] = b4.w;
    }
  }

  // ---- proj_in: z[k][dd] += sum_m x[k][m] * w_in[16s+dd][m] ----
  for (int mq = 0; mq < NMEL / 4; ++mq) {
    float4 xv[4];
#pragma unroll
    for (int k = 0; k < 4; ++k)
      xv[k] = *(const float4*)(mel + (size_t)(t0 + k) * NMEL + mq * 4);
#pragma unroll
    for (int dd = 0; dd < 16; ++dd) {
      const float4 wv = *(const float4*)(w_in + (s * 16 + dd) * NMEL + mq * 4);
#pragma unroll
      for (int k = 0; k < 4; ++k)
        z[k][dd] += xv[k].x * wv.x + xv[k].y * wv.y +
                    xv[k].z * wv.z + xv[k].w * wv.w;
    }
  }

  // ---- VQ stage helper: argmin_j ( nh[j] - <r, c_j> ) ----
  int b0i[4], b1i[4];
  auto run_stage = [&](const float* __restrict__ cb,
                       const float* __restrict__ nh, int* bi) {
    float bv[4] = {3.4e38f, 3.4e38f, 3.4e38f, 3.4e38f};
    int   lb[4] = {0, 0, 0, 0};
#pragma unroll 2
    for (int j = 0; j < NK; ++j) {
      const float4* cr = (const float4*)(cb + (size_t)j * ND + s * 16);
      const float4 c0v = cr[0], c1v = cr[1], c2v = cr[2], c3v = cr[3];
      float c[16];
      c[0]=c0v.x; c[1]=c0v.y; c[2]=c0v.z; c[3]=c0v.w;
      c[4]=c1v.x; c[5]=c1v.y; c[6]=c1v.z; c[7]=c1v.w;
      c[8]=c2v.x; c[9]=c2v.y; c[10]=c2v.z; c[11]=c2v.w;
      c[12]=c3v.x; c[13]=c3v.y; c[14]=c3v.z; c[15]=c3v.w;
      float p[4];
#pragma unroll
      for (int k = 0; k < 4; ++k) {
        float acc = 0.f;
#pragma unroll
        for (int dd = 0; dd < 16; ++dd) acc += z[k][dd] * c[dd];
        p[k] = acc;
      }
      // butterfly over the 4 slice lanes -> all lanes hold full dot
#pragma unroll
      for (int k = 0; k < 4; ++k) {
        p[k] += __shfl_xor(p[k], 1);
        p[k] += __shfl_xor(p[k], 2);
      }
      const float nhv = nh[j];   // wave-uniform -> scalar load
#pragma unroll
      for (int k = 0; k < 4; ++k) {
        const float sc = nhv - p[k];
        if (sc < bv[k]) { bv[k] = sc; lb[k] = j; }  // strict < = first min
      }
    }
#pragma unroll
    for (int k = 0; k < 4; ++k) bi[k] = lb[k];
  };

  // stage 1 vs cb0
  run_stage(cb0, n0h, b0i);
  // residual: z -= cb0[s0] slice (in place; z now holds r)
#pragma unroll
  for (int k = 0; k < 4; ++k) {
    const float4* cr = (const float4*)(cb0 + (size_t)b0i[k] * ND + s * 16);
#pragma unroll
    for (int u = 0; u < 4; ++u) {
      const float4 c4 = cr[u];
      z[k][u * 4 + 0] -= c4.x; z[k][u * 4 + 1] -= c4.y;
      z[k][u * 4 + 2] -= c4.z; z[k][u * 4 + 3] -= c4.w;
    }
  }
  // stage 2 vs cb1
  run_stage(cb1, n1h, b1i);

  // ---- epilogue: out_row = Dec0[s0] + Dec1[s1]  (b_out already in Dec0) ----
  // slice s writes columns [32s, 32s+32) of each of its 4 token rows.
#pragma unroll
  for (int k = 0; k < 4; ++k) {
    const float4* d0 = (const float4*)(dec0 + (size_t)b0i[k] * NMEL + s * 32);
    const float4* d1 = (const float4*)(dec1 + (size_t)b1i[k] * NMEL + s * 32);
    float4* orow = (float4*)(out + (size_t)(t0 + k) * NMEL + s * 32);
#pragma unroll
    for (int u = 0; u < 8; ++u) {
      const float4 a = d0[u];
      const float4 b = d1[u];
      float4 o;
      o.x = a.x + b.x; o.y = a.y + b.y; o.z = a.z + b.z; o.w = a.w + b.w;
      orow[u] = o;
    }
  }
}

}  // namespace

extern "C" void kernel_launch(void* const* d_in, const int* in_sizes, int n_in,
                              void* d_out, int out_size, void* d_ws, size_t ws_size,
                              hipStream_t stream) {
  const float* mel   = (const float*)d_in[0];
  const float* w_in  = (const float*)d_in[1];
  const float* b_in  = (const float*)d_in[2];
  const float* cb0   = (const float*)d_in[3];
  const float* cb1   = (const float*)d_in[4];
  const float* w_out = (const float*)d_in[5];
  const float* b_out = (const float*)d_in[6];
  float* out = (float*)d_out;

  // workspace layout: Dec0 (128x128 f32) | Dec1 (128x128) | n0h (128) | n1h (128)
  float* dec0 = (float*)d_ws;
  float* dec1 = dec0 + NK * NMEL;
  float* n0h  = dec1 + NK * NMEL;
  float* n1h  = n0h + NK;
  // requires 2*64KiB + 1KiB = ~132 KiB of workspace

  hipLaunchKernelGGL(precomp, dim3(NK), dim3(NMEL), 0, stream,
                     cb0, cb1, w_out, b_out, dec0, dec1, n0h, n1h);
  hipLaunchKernelGGL(rvq_main, dim3(GRID), dim3(BLK), 0, stream,
                     mel, w_in, b_in, cb0, cb1, dec0, dec1, n0h, n1h, out);
}

// Round 3
// 244.143 us; speedup vs baseline: 1.5762x; 1.5124x over previous
//
#include <hip/hip_runtime.h>

namespace {

typedef _Float16 v8h __attribute__((ext_vector_type(8)));
typedef float    v4f __attribute__((ext_vector_type(4)));

constexpr int NMEL = 128;
constexpr int ND   = 64;
constexpr int NK   = 128;
constexpr int NTOK = 32 * 4096;   // 131072

// ---------------------------------------------------------------------------
// precomp: build all token-independent tables into d_ws.
//   E[j][m]   = sum_d cb01[j][d] * w_in[d][m]          (fp32, then f16 hi/lo)
//   nh[j]     = 0.5*||c_j||^2 - b_in.c_j               (j in [0,256))
//   G[a][b]   = cb0[a].cb1[b]
//   Dec0[a][m]= cb0[a].w_out[m] + b_out[m],  Dec1[b][m]= cb1[b].w_out[m]
// grid 256 blocks x 128 threads; block j owns E row j (+ Dec/G rows).
// ---------------------------------------------------------------------------
__global__ void precomp(const float* __restrict__ w_in,
                        const float* __restrict__ b_in,
                        const float* __restrict__ cb0,
                        const float* __restrict__ cb1,
                        const float* __restrict__ w_out,
                        const float* __restrict__ b_out,
                        float* __restrict__ dec0, float* __restrict__ dec1,
                        float* __restrict__ G, float* __restrict__ nh,
                        _Float16* __restrict__ E_hi, _Float16* __restrict__ E_lo) {
  const int j = blockIdx.x;    // 0..255
  const int m = threadIdx.x;   // 0..127
  const float* crow = (j < NK) ? (cb0 + j * ND) : (cb1 + (j - NK) * ND);

  float e = 0.f, a = 0.f;
  for (int d = 0; d < ND; ++d) {
    const float cv = crow[d];                 // wave-uniform
    e += cv * w_in[d * NMEL + m];             // coalesced across threads
    a += cv * w_out[m * ND + d];
  }
  const _Float16 eh = (_Float16)e;
  E_hi[j * NMEL + m] = eh;
  E_lo[j * NMEL + m] = (_Float16)(e - (float)eh);

  if (j < NK) {
    dec0[j * NMEL + m] = a + b_out[m];
    float g = 0.f;
    for (int d = 0; d < ND; ++d) g += crow[d] * cb1[m * ND + d];
    G[j * NK + m] = g;
  } else {
    dec1[(j - NK) * NMEL + m] = a;
  }
  if (m == 0) {
    float s = 0.f, t = 0.f;
    for (int d = 0; d < ND; ++d) { s += crow[d] * crow[d]; t += b_in[d] * crow[d]; }
    nh[j] = 0.5f * s - t;
  }
}

// ---------------------------------------------------------------------------
// main: per wave, 16 tokens x 256 score cols via mfma_f32_16x16x32_f16 with
// fp16 hi/lo split (3 products). No LDS, no barriers.
// Fragment layouts (guide-verified): A[m=lane&15][k=quad*8+j],
// B[k=quad*8+j][n=lane&15], D[row=quad*4+i][col=lane&15].
// ---------------------------------------------------------------------------
__global__ __launch_bounds__(256) void rvq_main(
    const float* __restrict__ mel,
    const _Float16* __restrict__ E_hi,
    const _Float16* __restrict__ E_lo,
    const float* __restrict__ nh,
    const float* __restrict__ G,
    const float* __restrict__ dec0,
    const float* __restrict__ dec1,
    float* __restrict__ out) {
  const int tid  = threadIdx.x;
  const int wave = tid >> 6;
  const int lane = tid & 63;
  const int m    = lane & 15;   // A row within wave-tile / score col within c-tile
  const int q    = lane >> 4;   // quad
  const int tok0 = blockIdx.x * 64 + wave * 16;

  // ---- A fragments: load 16 tokens x 128 mel, split fp32 -> f16 hi+lo ----
  v8h a_hi[4], a_lo[4];
  {
    const float* xrow = mel + (size_t)(tok0 + m) * NMEL + q * 8;
#pragma unroll
    for (int kk = 0; kk < 4; ++kk) {
      const float4 x0 = *(const float4*)(xrow + kk * 32);
      const float4 x1 = *(const float4*)(xrow + kk * 32 + 4);
      const float xs[8] = {x0.x, x0.y, x0.z, x0.w, x1.x, x1.y, x1.z, x1.w};
#pragma unroll
      for (int e = 0; e < 8; ++e) {
        const _Float16 h = (_Float16)xs[e];
        a_hi[kk][e] = h;
        a_lo[kk][e] = (_Float16)(xs[e] - (float)h);  // exact residual, then RN
      }
    }
  }

  v4f acc[8];
  float bv[4];
  int   bi[4];
  int   s0i[4], s1i[4];

  // ================= stage 0: cols 0..127 =================
#pragma unroll
  for (int c = 0; c < 8; ++c) acc[c] = (v4f){0.f, 0.f, 0.f, 0.f};
#pragma unroll
  for (int c = 0; c < 8; ++c) {
    const _Float16* bh = E_hi + (size_t)(c * 16 + m) * NMEL + q * 8;
    const _Float16* bl = E_lo + (size_t)(c * 16 + m) * NMEL + q * 8;
#pragma unroll
    for (int kk = 0; kk < 4; ++kk) {
      const v8h bhv = *(const v8h*)(bh + kk * 32);
      const v8h blv = *(const v8h*)(bl + kk * 32);
      acc[c] = __builtin_amdgcn_mfma_f32_16x16x32_f16(a_hi[kk], bhv, acc[c], 0, 0, 0);
      acc[c] = __builtin_amdgcn_mfma_f32_16x16x32_f16(a_lo[kk], bhv, acc[c], 0, 0, 0);
      acc[c] = __builtin_amdgcn_mfma_f32_16x16x32_f16(a_hi[kk], blv, acc[c], 0, 0, 0);
    }
  }
  // argmin_j ( nh[j] - S_j ), j = c*16 + m
#pragma unroll
  for (int i = 0; i < 4; ++i) { bv[i] = 3.4e38f; bi[i] = 0; }
#pragma unroll
  for (int c = 0; c < 8; ++c) {
    const float nv = nh[c * 16 + m];
#pragma unroll
    for (int i = 0; i < 4; ++i) {
      const float sc = nv - acc[c][i];
      if (sc < bv[i]) { bv[i] = sc; bi[i] = c * 16 + m; }
    }
  }
#pragma unroll
  for (int d = 1; d < 16; d <<= 1) {
#pragma unroll
    for (int i = 0; i < 4; ++i) {
      const float ov = __shfl_xor(bv[i], d);
      const int   oi = __shfl_xor(bi[i], d);
      if (ov < bv[i] || (ov == bv[i] && oi < bi[i])) { bv[i] = ov; bi[i] = oi; }
    }
  }
#pragma unroll
  for (int i = 0; i < 4; ++i) s0i[i] = bi[i];

  // ---- preload G rows for stage 1 (independent of stage-1 MFMAs) ----
  float gv[4][8];
#pragma unroll
  for (int i = 0; i < 4; ++i) {
    const float* grow = G + (size_t)s0i[i] * NK + m;
#pragma unroll
    for (int c = 0; c < 8; ++c) gv[i][c] = grow[c * 16];
  }

  // ================= stage 1: cols 128..255 =================
#pragma unroll
  for (int c = 0; c < 8; ++c) acc[c] = (v4f){0.f, 0.f, 0.f, 0.f};
#pragma unroll
  for (int c = 0; c < 8; ++c) {
    const _Float16* bh = E_hi + (size_t)(NK + c * 16 + m) * NMEL + q * 8;
    const _Float16* bl = E_lo + (size_t)(NK + c * 16 + m) * NMEL + q * 8;
#pragma unroll
    for (int kk = 0; kk < 4; ++kk) {
      const v8h bhv = *(const v8h*)(bh + kk * 32);
      const v8h blv = *(const v8h*)(bl + kk * 32);
      acc[c] = __builtin_amdgcn_mfma_f32_16x16x32_f16(a_hi[kk], bhv, acc[c], 0, 0, 0);
      acc[c] = __builtin_amdgcn_mfma_f32_16x16x32_f16(a_lo[kk], bhv, acc[c], 0, 0, 0);
      acc[c] = __builtin_amdgcn_mfma_f32_16x16x32_f16(a_hi[kk], blv, acc[c], 0, 0, 0);
    }
  }
  // argmin_j ( nh[128+j] + G[s0][j] - S_{128+j} )
#pragma unroll
  for (int i = 0; i < 4; ++i) { bv[i] = 3.4e38f; bi[i] = 0; }
#pragma unroll
  for (int c = 0; c < 8; ++c) {
    const float nv = nh[NK + c * 16 + m];
#pragma unroll
    for (int i = 0; i < 4; ++i) {
      const float sc = nv + gv[i][c] - acc[c][i];
      if (sc < bv[i]) { bv[i] = sc; bi[i] = c * 16 + m; }
    }
  }
#pragma unroll
  for (int d = 1; d < 16; d <<= 1) {
#pragma unroll
    for (int i = 0; i < 4; ++i) {
      const float ov = __shfl_xor(bv[i], d);
      const int   oi = __shfl_xor(bi[i], d);
      if (ov < bv[i] || (ov == bv[i] && oi < bi[i])) { bv[i] = ov; bi[i] = oi; }
    }
  }
#pragma unroll
  for (int i = 0; i < 4; ++i) s1i[i] = bi[i];

  // ---- epilogue: out_row = Dec0[s0] + Dec1[s1]; lane writes cols [8m,8m+8) ----
#pragma unroll
  for (int i = 0; i < 4; ++i) {
    const int t = tok0 + q * 4 + i;
    const float4* p0 = (const float4*)(dec0 + (size_t)s0i[i] * NMEL + m * 8);
    const float4* p1 = (const float4*)(dec1 + (size_t)s1i[i] * NMEL + m * 8);
    float4* o = (float4*)(out + (size_t)t * NMEL + m * 8);
    const float4 u0 = p0[0], u1 = p0[1], w0 = p1[0], w1 = p1[1];
    float4 r0, r1;
    r0.x = u0.x + w0.x; r0.y = u0.y + w0.y; r0.z = u0.z + w0.z; r0.w = u0.w + w0.w;
    r1.x = u1.x + w1.x; r1.y = u1.y + w1.y; r1.z = u1.z + w1.z; r1.w = u1.w + w1.w;
    o[0] = r0; o[1] = r1;
  }
}

}  // namespace

extern "C" void kernel_launch(void* const* d_in, const int* in_sizes, int n_in,
                              void* d_out, int out_size, void* d_ws, size_t ws_size,
                              hipStream_t stream) {
  const float* mel   = (const float*)d_in[0];
  const float* w_in  = (const float*)d_in[1];
  const float* b_in  = (const float*)d_in[2];
  const float* cb0   = (const float*)d_in[3];
  const float* cb1   = (const float*)d_in[4];
  const float* w_out = (const float*)d_in[5];
  const float* b_out = (const float*)d_in[6];
  float* out = (float*)d_out;

  // ws layout: dec0 | dec1 | G | nh | E_hi | E_lo  (~328 KB total)
  float* dec0 = (float*)d_ws;
  float* dec1 = dec0 + NK * NMEL;
  float* G    = dec1 + NK * NMEL;
  float* nh   = G + NK * NK;
  _Float16* E_hi = (_Float16*)(nh + 2 * NK);
  _Float16* E_lo = E_hi + 2 * NK * NMEL;

  hipLaunchKernelGGL(precomp, dim3(2 * NK), dim3(NMEL), 0, stream,
                     w_in, b_in, cb0, cb1, w_out, b_out,
                     dec0, dec1, G, nh, E_hi, E_lo);
  hipLaunchKernelGGL(rvq_main, dim3(NTOK / 64), dim3(256), 0, stream,
                     mel, E_hi, E_lo, nh, G, dec0, dec1, out);
}

// Round 4
// 157.122 us; speedup vs baseline: 2.4491x; 1.5538x over previous
//
#include <hip/hip_runtime.h>

namespace {

typedef _Float16 v8h __attribute__((ext_vector_type(8)));
typedef float    v4f __attribute__((ext_vector_type(4)));

constexpr int NMEL = 128;
constexpr int ND   = 64;
constexpr int NK   = 128;
constexpr int NTOK = 32 * 4096;          // 131072
constexpr int TPB  = 128;                // tokens per block
constexpr int GRID = NTOK / TPB;         // 1024

// ---------------------------------------------------------------------------
// precomp: all token-independent tables into d_ws.
//   E[j][m] = sum_d cb01[j][d]*w_in[d][m] -> f16 hi/lo, stored SWIZZLED in
//   MFMA-fragment order: chunk(s,c,h,kk) of 1 KB; element lane*16B + e*2B
//   holds E[s*128 + c*16 + (lane&15)][kk*32 + (lane>>4)*8 + e].
//   nh[j] = 0.5||c_j||^2 - b_in.c_j ; G[a][b] = cb0_a.cb1_b ;
//   Dec0[a][m] = cb0_a.w_out_m + b_out_m ; Dec1[b][m] = cb1_b.w_out_m.
// ---------------------------------------------------------------------------
__global__ __launch_bounds__(256) void precomp(
    const float* __restrict__ w_in, const float* __restrict__ b_in,
    const float* __restrict__ cb0, const float* __restrict__ cb1,
    const float* __restrict__ w_out, const float* __restrict__ b_out,
    float* __restrict__ dec0, float* __restrict__ dec1,
    float* __restrict__ G, float* __restrict__ nh,
    _Float16* __restrict__ E_swz) {
  const int j = blockIdx.x;          // 0..255
  const int tid = threadIdx.x;
  const float* __restrict__ crow = (j < NK) ? (cb0 + j * ND) : (cb1 + (j - NK) * ND);

  if (tid < NMEL) {
    const int m = tid;
    float e = 0.f;
#pragma unroll 8
    for (int d = 0; d < ND; ++d) e += crow[d] * w_in[d * NMEL + m];
    const _Float16 hi = (_Float16)e;
    const _Float16 lo = (_Float16)(e - (float)hi);
    const int s = j >> 7, jj = j & 127, c = jj >> 4, mr = jj & 15;
    const int kk = m >> 5, q = (m >> 3) & 3, ei = m & 7;
    const int lane = q * 16 + mr;
    const size_t base = ((((size_t)s * 8 + c) * 8) + kk) * 512;  // h=0 chunk (halves)
    E_swz[base + lane * 8 + ei] = hi;
    E_swz[base + 2048 + lane * 8 + ei] = lo;                     // h=1 chunk
  } else {
    const int m = tid - NMEL;
    const float4* wr = (const float4*)(w_out + m * ND);
    const float4* cr4 = (const float4*)crow;
    float a = 0.f;
#pragma unroll
    for (int qq = 0; qq < ND / 4; ++qq) {
      const float4 w4 = wr[qq], c4 = cr4[qq];
      a += c4.x * w4.x + c4.y * w4.y + c4.z * w4.z + c4.w * w4.w;
    }
    if (j < NK) dec0[j * NMEL + m] = a + b_out[m];
    else        dec1[(j - NK) * NMEL + m] = a;
    if (j < NK) {
      const float4* c1r = (const float4*)(cb1 + m * ND);
      float g = 0.f;
#pragma unroll
      for (int qq = 0; qq < ND / 4; ++qq) {
        const float4 c4 = cr4[qq], d4 = c1r[qq];
        g += c4.x * d4.x + c4.y * d4.y + c4.z * d4.z + c4.w * d4.w;
      }
      G[j * NK + m] = g;
    }
  }
  if (tid < 64) {  // whole first wave: nh[j] via butterfly reduce
    const float v = crow[tid];
    float t = 0.5f * v * v - b_in[tid] * v;
#pragma unroll
    for (int d = 1; d < 64; d <<= 1) t += __shfl_xor(t, d);
    if (tid == 0) nh[j] = t;
  }
}

// ---------------------------------------------------------------------------
// main: block = 256 thr (4 waves), 128 tokens (2 tiles of 16 per wave).
// E staged per stage in 64 KB LDS (fragment order -> conflict-free b128).
// ---------------------------------------------------------------------------
__global__ __launch_bounds__(256, 2) void rvq_main(
    const float* __restrict__ mel,
    const _Float16* __restrict__ E_swz,
    const float* __restrict__ nh,
    const float* __restrict__ G,
    const float* __restrict__ dec0,
    const float* __restrict__ dec1,
    float* __restrict__ out) {
  __shared__ _Float16 sE[32768];   // 64 KB = one stage of E (hi+lo)
  const int tid = threadIdx.x;
  const int wv = tid >> 6;
  const int ln = tid & 63;
  const int m  = ln & 15;
  const int q  = ln >> 4;

  // ---- issue stage-0 fill (direct-to-LDS DMA, contiguous) ----
  {
    const char* g = (const char*)E_swz;
    char* l = (char*)sE;
#pragma unroll
    for (int it = 0; it < 16; ++it) {
      __builtin_amdgcn_global_load_lds(
          (const __attribute__((address_space(1))) void*)(g + it * 4096 + wv * 1024 + ln * 16),
          (__attribute__((address_space(3))) void*)(l + it * 4096 + wv * 1024),
          16, 0, 0);
    }
  }

  // ---- A fragments: 2 tiles x 16 tokens, fp32 -> f16 hi+lo ----
  v8h a_hi[2][4], a_lo[2][4];
#pragma unroll
  for (int t = 0; t < 2; ++t) {
    const int tok0 = blockIdx.x * TPB + wv * 32 + t * 16;
    const float* xr = mel + (size_t)(tok0 + m) * NMEL + q * 8;
#pragma unroll
    for (int kk = 0; kk < 4; ++kk) {
      const float4 x0 = *(const float4*)(xr + kk * 32);
      const float4 x1 = *(const float4*)(xr + kk * 32 + 4);
      const float xs[8] = {x0.x, x0.y, x0.z, x0.w, x1.x, x1.y, x1.z, x1.w};
#pragma unroll
      for (int e = 0; e < 8; ++e) {
        const _Float16 h = (_Float16)xs[e];
        a_hi[t][kk][e] = h;
        a_lo[t][kk][e] = (_Float16)(xs[e] - (float)h);
      }
    }
  }

  float nhv[8];
#pragma unroll
  for (int c = 0; c < 8; ++c) nhv[c] = nh[c * 16 + m];

  float bv[2][4];
  int   bi[2][4];
  int   s0i[2][4], s1i[2][4];

  __syncthreads();   // fill complete

  // ================= stage 0 =================
#pragma unroll
  for (int t = 0; t < 2; ++t)
#pragma unroll
    for (int i = 0; i < 4; ++i) { bv[t][i] = 3.4e38f; bi[t][i] = 0; }

#pragma unroll
  for (int c = 0; c < 8; ++c) {
    v8h bh[4], bl[4];
#pragma unroll
    for (int kk = 0; kk < 4; ++kk) {
      bh[kk] = *(const v8h*)(sE + (c * 8 + kk) * 512 + ln * 8);
      bl[kk] = *(const v8h*)(sE + (c * 8 + 4 + kk) * 512 + ln * 8);
    }
    v4f a0 = (v4f){0.f, 0.f, 0.f, 0.f}, a1 = a0;
#pragma unroll
    for (int kk = 0; kk < 4; ++kk) {
      a0 = __builtin_amdgcn_mfma_f32_16x16x32_f16(a_hi[0][kk], bh[kk], a0, 0, 0, 0);
      a1 = __builtin_amdgcn_mfma_f32_16x16x32_f16(a_hi[1][kk], bh[kk], a1, 0, 0, 0);
      a0 = __builtin_amdgcn_mfma_f32_16x16x32_f16(a_lo[0][kk], bh[kk], a0, 0, 0, 0);
      a1 = __builtin_amdgcn_mfma_f32_16x16x32_f16(a_lo[1][kk], bh[kk], a1, 0, 0, 0);
      a0 = __builtin_amdgcn_mfma_f32_16x16x32_f16(a_hi[0][kk], bl[kk], a0, 0, 0, 0);
      a1 = __builtin_amdgcn_mfma_f32_16x16x32_f16(a_hi[1][kk], bl[kk], a1, 0, 0, 0);
    }
    const float nv = nhv[c];
    const int jj = c * 16 + m;
#pragma unroll
    for (int i = 0; i < 4; ++i) {
      const float s0 = nv - a0[i];
      if (s0 < bv[0][i]) { bv[0][i] = s0; bi[0][i] = jj; }
      const float s1 = nv - a1[i];
      if (s1 < bv[1][i]) { bv[1][i] = s1; bi[1][i] = jj; }
    }
  }
#pragma unroll
  for (int d = 1; d < 16; d <<= 1)
#pragma unroll
    for (int t = 0; t < 2; ++t)
#pragma unroll
      for (int i = 0; i < 4; ++i) {
        const float ov = __shfl_xor(bv[t][i], d);
        const int   oi = __shfl_xor(bi[t][i], d);
        if (ov < bv[t][i] || (ov == bv[t][i] && oi < bi[t][i])) { bv[t][i] = ov; bi[t][i] = oi; }
      }
#pragma unroll
  for (int t = 0; t < 2; ++t)
#pragma unroll
    for (int i = 0; i < 4; ++i) s0i[t][i] = bi[t][i];

  __syncthreads();   // all waves done reading stage-0 LDS

  // ---- issue stage-1 fill; overlap with nh/G preloads ----
  {
    const char* g = (const char*)(E_swz + 32768);
    char* l = (char*)sE;
#pragma unroll
    for (int it = 0; it < 16; ++it) {
      __builtin_amdgcn_global_load_lds(
          (const __attribute__((address_space(1))) void*)(g + it * 4096 + wv * 1024 + ln * 16),
          (__attribute__((address_space(3))) void*)(l + it * 4096 + wv * 1024),
          16, 0, 0);
    }
  }
#pragma unroll
  for (int c = 0; c < 8; ++c) nhv[c] = nh[NK + c * 16 + m];
  float gc[2][4];
#pragma unroll
  for (int t = 0; t < 2; ++t)
#pragma unroll
    for (int i = 0; i < 4; ++i) gc[t][i] = G[(size_t)s0i[t][i] * NK + m];  // c=0

  __syncthreads();   // stage-1 fill complete

  // ================= stage 1 =================
#pragma unroll
  for (int t = 0; t < 2; ++t)
#pragma unroll
    for (int i = 0; i < 4; ++i) { bv[t][i] = 3.4e38f; bi[t][i] = 0; }

#pragma unroll
  for (int c = 0; c < 8; ++c) {
    v8h bh[4], bl[4];
#pragma unroll
    for (int kk = 0; kk < 4; ++kk) {
      bh[kk] = *(const v8h*)(sE + (c * 8 + kk) * 512 + ln * 8);
      bl[kk] = *(const v8h*)(sE + (c * 8 + 4 + kk) * 512 + ln * 8);
    }
    float gn[2][4];
    if (c < 7) {
#pragma unroll
      for (int t = 0; t < 2; ++t)
#pragma unroll
        for (int i = 0; i < 4; ++i)
          gn[t][i] = G[(size_t)s0i[t][i] * NK + (c + 1) * 16 + m];
    }
    v4f a0 = (v4f){0.f, 0.f, 0.f, 0.f}, a1 = a0;
#pragma unroll
    for (int kk = 0; kk < 4; ++kk) {
      a0 = __builtin_amdgcn_mfma_f32_16x16x32_f16(a_hi[0][kk], bh[kk], a0, 0, 0, 0);
      a1 = __builtin_amdgcn_mfma_f32_16x16x32_f16(a_hi[1][kk], bh[kk], a1, 0, 0, 0);
      a0 = __builtin_amdgcn_mfma_f32_16x16x32_f16(a_lo[0][kk], bh[kk], a0, 0, 0, 0);
      a1 = __builtin_amdgcn_mfma_f32_16x16x32_f16(a_lo[1][kk], bh[kk], a1, 0, 0, 0);
      a0 = __builtin_amdgcn_mfma_f32_16x16x32_f16(a_hi[0][kk], bl[kk], a0, 0, 0, 0);
      a1 = __builtin_amdgcn_mfma_f32_16x16x32_f16(a_hi[1][kk], bl[kk], a1, 0, 0, 0);
    }
    const float nv = nhv[c];
    const int jj = c * 16 + m;
#pragma unroll
    for (int i = 0; i < 4; ++i) {
      const float s0 = nv + gc[0][i] - a0[i];
      if (s0 < bv[0][i]) { bv[0][i] = s0; bi[0][i] = jj; }
      const float s1 = nv + gc[1][i] - a1[i];
      if (s1 < bv[1][i]) { bv[1][i] = s1; bi[1][i] = jj; }
    }
    if (c < 7) {
#pragma unroll
      for (int t = 0; t < 2; ++t)
#pragma unroll
        for (int i = 0; i < 4; ++i) gc[t][i] = gn[t][i];
    }
  }
#pragma unroll
  for (int d = 1; d < 16; d <<= 1)
#pragma unroll
    for (int t = 0; t < 2; ++t)
#pragma unroll
      for (int i = 0; i < 4; ++i) {
        const float ov = __shfl_xor(bv[t][i], d);
        const int   oi = __shfl_xor(bi[t][i], d);
        if (ov < bv[t][i] || (ov == bv[t][i] && oi < bi[t][i])) { bv[t][i] = ov; bi[t][i] = oi; }
      }
#pragma unroll
  for (int t = 0; t < 2; ++t)
#pragma unroll
    for (int i = 0; i < 4; ++i) s1i[t][i] = bi[t][i];

  // ---- epilogue: out = Dec0[s0] + Dec1[s1] ----
#pragma unroll
  for (int t = 0; t < 2; ++t)
#pragma unroll
    for (int i = 0; i < 4; ++i) {
      const int tok = blockIdx.x * TPB + wv * 32 + t * 16 + q * 4 + i;
      const float4* p0 = (const float4*)(dec0 + (size_t)s0i[t][i] * NMEL + m * 8);
      const float4* p1 = (const float4*)(dec1 + (size_t)s1i[t][i] * NMEL + m * 8);
      float4* o = (float4*)(out + (size_t)tok * NMEL + m * 8);
      const float4 u0 = p0[0], u1 = p0[1], w0 = p1[0], w1 = p1[1];
      float4 r0, r1;
      r0.x = u0.x + w0.x; r0.y = u0.y + w0.y; r0.z = u0.z + w0.z; r0.w = u0.w + w0.w;
      r1.x = u1.x + w1.x; r1.y = u1.y + w1.y; r1.z = u1.z + w1.z; r1.w = u1.w + w1.w;
      o[0] = r0; o[1] = r1;
    }
}

}  // namespace

extern "C" void kernel_launch(void* const* d_in, const int* in_sizes, int n_in,
                              void* d_out, int out_size, void* d_ws, size_t ws_size,
                              hipStream_t stream) {
  const float* mel   = (const float*)d_in[0];
  const float* w_in  = (const float*)d_in[1];
  const float* b_in  = (const float*)d_in[2];
  const float* cb0   = (const float*)d_in[3];
  const float* cb1   = (const float*)d_in[4];
  const float* w_out = (const float*)d_in[5];
  const float* b_out = (const float*)d_in[6];
  float* out = (float*)d_out;

  // ws: dec0 | dec1 | G | nh | E_swz  (64+64+64+1+128 KB ~ 321 KB)
  float* dec0 = (float*)d_ws;
  float* dec1 = dec0 + NK * NMEL;
  float* G    = dec1 + NK * NMEL;
  float* nh   = G + NK * NK;
  _Float16* E_swz = (_Float16*)(nh + 2 * NK);

  hipLaunchKernelGGL(precomp, dim3(2 * NK), dim3(256), 0, stream,
                     w_in, b_in, cb0, cb1, w_out, b_out, dec0, dec1, G, nh, E_swz);
  hipLaunchKernelGGL(rvq_main, dim3(GRID), dim3(256), 0, stream,
                     mel, E_swz, nh, G, dec0, dec1, out);
}